// Round 3
// baseline (177.002 us; speedup 1.0000x reference)
//
#include <hip/hip_runtime.h>

// SpatialEngram: out[b,o,i,j] = (table @ proj_w.T + proj_b)[idx[b,i,j]][o]
// where idx = trunc(mean_c(abs(3x3_sum(trunc(x*100)))%P))
//
// Strategy:
//   Kernel 1: table_proj[P][64] = table @ proj_w.T + proj_b  (into d_ws, 2.56 MB)
//   Kernel 2: fused quantize + 3x3 window sum + mod + channel-mean + gather + write.
//             64x4 tile per block, LDS-staged q tile per channel (double-buffered),
//             wave = one 64-wide row -> coalesced 256B stores per output plane.

#define CH  32
#define HH  512
#define WW  512
#define EE  64
#define OUT 64
#define PP  10000

#define TW 64
#define TH 4
#define LW (TW + 2)   // 66
#define LH (TH + 2)   // 6

__global__ __launch_bounds__(256) void proj_table_kernel(
    const float* __restrict__ table, const float* __restrict__ pw,
    const float* __restrict__ pb, float* __restrict__ tp) {
  __shared__ float sW[EE * OUT];          // transposed: sW[e*64 + o] = pw[o*64 + e]
  const int t = threadIdx.x;              // 0..255
  for (int i = t; i < EE * OUT; i += 256) {
    int o = i >> 6, e = i & 63;
    sW[e * OUT + o] = pw[i];
  }
  __syncthreads();
  const int p = blockIdx.x * 4 + (t >> 6);
  const int o = t & 63;
  const float* trow = table + (size_t)p * EE;
  float s = pb[o];
  #pragma unroll
  for (int e = 0; e < EE; ++e)
    s = fmaf(trow[e], sW[e * OUT + o], s);   // lanes o consecutive -> conflict-free
  tp[(size_t)p * OUT + o] = s;
}

__global__ __launch_bounds__(256) void engram_kernel(
    const float* __restrict__ x, const float* __restrict__ tp,
    float* __restrict__ out) {
  __shared__ int q[2][LH][LW];
  const int tx  = threadIdx.x;             // 0..63
  const int ty  = threadIdx.y;             // 0..3
  const int t   = ty * TW + tx;            // 0..255
  const int gx0 = blockIdx.x * TW;
  const int gy0 = blockIdx.y * TH;
  const int b   = blockIdx.z;

  const int gx = gx0 + tx;
  const int gy = gy0 + ty;

  const float* xb = x + (size_t)b * CH * HH * WW;

  int acc = 0;
  for (int c = 0; c < CH; ++c) {
    const float* xc = xb + (size_t)c * HH * WW;
    int (*buf)[LW] = q[c & 1];
    // stage (TH+2)x(TW+2) quantized tile with replicate clamping
    for (int e = t; e < LH * LW; e += 256) {
      int ly = e / LW, lx = e - ly * LW;
      int yy = gy0 + ly - 1; yy = min(max(yy, 0), HH - 1);
      int xx = gx0 + lx - 1; xx = min(max(xx, 0), WW - 1);
      buf[ly][lx] = (int)(xc[(size_t)yy * WW + xx] * 100.0f);  // trunc toward zero
    }
    __syncthreads();   // double-buffered: one barrier per channel is sufficient
    int hsum = 0;
    #pragma unroll
    for (int dy = 0; dy < 3; ++dy)
      #pragma unroll
      for (int dx = 0; dx < 3; ++dx)
        hsum += buf[ty + dy][tx + dx];
    int m = (hsum < 0 ? -hsum : hsum) % PP;
    acc += m;
  }
  // mean over 32 channels (exact in f32) then trunc -> acc >> 5 (acc >= 0)
  const int idx = acc >> 5;

  const float4* row = (const float4*)(tp + (size_t)idx * OUT);
  float* ob = out + (size_t)b * OUT * HH * WW + (size_t)gy * WW + gx;
  #pragma unroll
  for (int o4 = 0; o4 < 16; ++o4) {
    float4 v = row[o4];
    ob[(size_t)(o4 * 4 + 0) * HH * WW] = v.x;
    ob[(size_t)(o4 * 4 + 1) * HH * WW] = v.y;
    ob[(size_t)(o4 * 4 + 2) * HH * WW] = v.z;
    ob[(size_t)(o4 * 4 + 3) * HH * WW] = v.w;
  }
}

extern "C" void kernel_launch(void* const* d_in, const int* in_sizes, int n_in,
                              void* d_out, int out_size, void* d_ws, size_t ws_size,
                              hipStream_t stream) {
  const float* x     = (const float*)d_in[0];  // (4,32,512,512)
  const float* table = (const float*)d_in[1];  // (10000,64)
  const float* pw    = (const float*)d_in[2];  // (64,64)
  const float* pb    = (const float*)d_in[3];  // (64,)
  float* out = (float*)d_out;                  // (4,64,512,512)

  const int B = in_sizes[0] / (CH * HH * WW);  // 4

  float* tp = (float*)d_ws;                    // needs PP*OUT*4 = 2.56 MB

  proj_table_kernel<<<PP / 4, 256, 0, stream>>>(table, pw, pb, tp);

  dim3 block(TW, TH, 1);
  dim3 grid(WW / TW, HH / TH, B);              // (8, 128, 4)
  engram_kernel<<<grid, block, 0, stream>>>(x, tp, out);
}

// Round 5
// 108.047 us; speedup vs baseline: 1.6382x; 1.6382x over previous
//
#include <hip/hip_runtime.h>

// SpatialEngram: out[b,o,i,j] = (table @ proj_w.T + proj_b)[idx[b,i,j]][o]
// where idx = trunc(mean_c(abs(3x3_sum(trunc(x*100)))%P))
//
// Round 4: Round-3 restructure + compile fix (nontemporal store needs a
// native clang vector type, not HIP_vector_type).
//   - 4 px per thread along x: one float4 load per q-row per channel.
//   - 3x3 sum via 4 register column-sums + 2 wave shuffles (neighbor cols).
//     Edge lanes (tx==0/63) take 3 predicated clamped scalar loads
//     (clamp == replicate padding).
//   - Epilogue: gather 4 tp rows (float4), register transpose, float4
//     nontemporal stores (protect tp's L2 residency from the write stream).
//   - proj_table: 4 accumulators + float4 loads to break the fmaf chain.

#define CH  32
#define HH  512
#define WW  512
#define EE  64
#define OUT 64
#define PP  10000

#define TWPX 256              // tile width in pixels (64 threads x 4 px)
#define HW   (HH * WW)

typedef float f32x4 __attribute__((ext_vector_type(4)));

__global__ __launch_bounds__(256) void proj_table_kernel(
    const float* __restrict__ table, const float* __restrict__ pw,
    const float* __restrict__ pb, float* __restrict__ tp) {
  __shared__ float sW[EE * OUT];          // sW[e*64 + o] = pw[o*64 + e]
  const int t = threadIdx.x;              // 0..255
  for (int i = t; i < EE * OUT; i += 256) {
    int o = i >> 6, e = i & 63;
    sW[e * OUT + o] = pw[i];
  }
  __syncthreads();
  const int p = blockIdx.x * 4 + (t >> 6);
  const int o = t & 63;
  const float4* trow = (const float4*)(table + (size_t)p * EE);
  float s0 = pb[o], s1 = 0.f, s2 = 0.f, s3 = 0.f;
  #pragma unroll
  for (int e4 = 0; e4 < EE / 4; ++e4) {
    float4 tv = trow[e4];                 // wave-uniform per 64-lane group
    s0 = fmaf(tv.x, sW[(4 * e4 + 0) * OUT + o], s0);
    s1 = fmaf(tv.y, sW[(4 * e4 + 1) * OUT + o], s1);
    s2 = fmaf(tv.z, sW[(4 * e4 + 2) * OUT + o], s2);
    s3 = fmaf(tv.w, sW[(4 * e4 + 3) * OUT + o], s3);
  }
  tp[(size_t)p * OUT + o] = (s0 + s1) + (s2 + s3);
}

__device__ __forceinline__ int q3(float a, float b, float c) {
  // column sum of trunc(v*100) over 3 rows; (int) truncates toward zero
  return (int)(a * 100.0f) + (int)(b * 100.0f) + (int)(c * 100.0f);
}

__device__ __forceinline__ void nt_store4(float* p, float a, float b, float c, float d) {
  f32x4 v = {a, b, c, d};
  __builtin_nontemporal_store(v, (f32x4*)p);
}

__global__ __launch_bounds__(256) void engram_kernel(
    const float* __restrict__ x, const float* __restrict__ tp,
    float* __restrict__ out) {
  const int tx  = threadIdx.x;            // 0..63
  const int ty  = threadIdx.y;            // 0..3
  const int gx0 = blockIdx.x * TWPX;
  const int y   = blockIdx.y * 4 + ty;
  const int b   = blockIdx.z;
  const int x0  = gx0 + tx * 4;

  const int ym1 = max(y - 1, 0);
  const int yp1 = min(y + 1, HH - 1);
  const size_t rm1 = (size_t)ym1 * WW + x0;
  const size_t r0  = (size_t)y   * WW + x0;
  const size_t rp1 = (size_t)yp1 * WW + x0;

  const bool edge = (tx == 0) || (tx == 63);
  const int  ecol = (tx == 0) ? max(gx0 - 1, 0) : min(gx0 + TWPX, WW - 1);
  const size_t em1 = (size_t)ym1 * WW + ecol;
  const size_t e0  = (size_t)y   * WW + ecol;
  const size_t ep1 = (size_t)yp1 * WW + ecol;

  const float* xb = x + (size_t)b * CH * HW;

  int acc0 = 0, acc1 = 0, acc2 = 0, acc3 = 0;
  #pragma unroll 2
  for (int c = 0; c < CH; ++c) {
    const float* xc = xb + (size_t)c * HW;
    float4 a = *(const float4*)(xc + rm1);
    float4 m = *(const float4*)(xc + r0);
    float4 p = *(const float4*)(xc + rp1);

    int cs0 = q3(a.x, m.x, p.x);
    int cs1 = q3(a.y, m.y, p.y);
    int cs2 = q3(a.z, m.z, p.z);
    int cs3 = q3(a.w, m.w, p.w);

    int csl = __shfl(cs3, tx - 1, 64);    // junk for tx==0 (overwritten)
    int csr = __shfl(cs0, tx + 1, 64);    // junk for tx==63 (overwritten)
    if (edge) {
      int e = q3(xc[em1], xc[e0], xc[ep1]);
      if (tx == 0) csl = e; else csr = e;
    }

    int h0 = csl + cs0 + cs1;
    int h1 = cs0 + cs1 + cs2;
    int h2 = cs1 + cs2 + cs3;
    int h3 = cs2 + cs3 + csr;

    acc0 += (int)((unsigned)(h0 < 0 ? -h0 : h0) % PP);
    acc1 += (int)((unsigned)(h1 < 0 ? -h1 : h1) % PP);
    acc2 += (int)((unsigned)(h2 < 0 ? -h2 : h2) % PP);
    acc3 += (int)((unsigned)(h3 < 0 ? -h3 : h3) % PP);
  }
  // mean over 32 channels, exact in f32; trunc of nonneg == >>5
  const int i0 = acc0 >> 5, i1 = acc1 >> 5, i2 = acc2 >> 5, i3 = acc3 >> 5;

  const float4* t0 = (const float4*)(tp + (size_t)i0 * OUT);
  const float4* t1 = (const float4*)(tp + (size_t)i1 * OUT);
  const float4* t2 = (const float4*)(tp + (size_t)i2 * OUT);
  const float4* t3 = (const float4*)(tp + (size_t)i3 * OUT);

  float* ob = out + (size_t)b * OUT * HW + (size_t)y * WW + x0;
  #pragma unroll 4
  for (int k = 0; k < OUT / 4; ++k) {
    float4 va = t0[k], vb = t1[k], vc = t2[k], vd = t3[k];
    float* o0 = ob + (size_t)(4 * k) * HW;
    nt_store4(o0,          va.x, vb.x, vc.x, vd.x);
    nt_store4(o0 + HW,     va.y, vb.y, vc.y, vd.y);
    nt_store4(o0 + 2 * HW, va.z, vb.z, vc.z, vd.z);
    nt_store4(o0 + 3 * HW, va.w, vb.w, vc.w, vd.w);
  }
}

extern "C" void kernel_launch(void* const* d_in, const int* in_sizes, int n_in,
                              void* d_out, int out_size, void* d_ws, size_t ws_size,
                              hipStream_t stream) {
  const float* x     = (const float*)d_in[0];  // (4,32,512,512)
  const float* table = (const float*)d_in[1];  // (10000,64)
  const float* pw    = (const float*)d_in[2];  // (64,64)
  const float* pb    = (const float*)d_in[3];  // (64,)
  float* out = (float*)d_out;                  // (4,64,512,512)

  const int B = in_sizes[0] / (CH * HW);       // 4

  float* tp = (float*)d_ws;                    // PP*OUT*4 = 2.56 MB

  proj_table_kernel<<<PP / 4, 256, 0, stream>>>(table, pw, pb, tp);

  dim3 block(64, 4, 1);
  dim3 grid(WW / TWPX, HH / 4, B);             // (2, 128, 4)
  engram_kernel<<<grid, block, 0, stream>>>(x, tp, out);
}